// Round 1
// baseline (480.119 us; speedup 1.0000x reference)
//
#include <hip/hip_runtime.h>
#include <hip/hip_bf16.h>

// Problem constants (B, C, H, W, K) = (16, 512, 64, 64, 32)
#define BB   16
#define CC   512
#define HWN  4096        // H*W
#define KK   32
#define EPSF 1e-5f

typedef short bf16x8 __attribute__((ext_vector_type(8)));
typedef float f32x4  __attribute__((ext_vector_type(4)));

static __device__ __forceinline__ unsigned short f2b(float f) {
    unsigned u = __builtin_bit_cast(unsigned, f);
    unsigned r = (u + 0x7FFFu + ((u >> 16) & 1u)) >> 16;   // RNE
    return (unsigned short)r;
}
static __device__ __forceinline__ float b2f(unsigned short s) {
    unsigned u = ((unsigned)s) << 16;
    return __builtin_bit_cast(float, u);
}

// ---------------- K0a: convert conv_w (fp32, [o][c]) -> bf16 ----------------
__global__ __launch_bounds__(256) void k_convert_w(const float* __restrict__ W,
                                                   unsigned short* __restrict__ Wb) {
    int i = (blockIdx.x * 256 + threadIdx.x) * 4;   // 262144 elements total
    float4 v = *(const float4*)(W + i);
    unsigned lo = (unsigned)f2b(v.x) | ((unsigned)f2b(v.y) << 16);
    unsigned hi = (unsigned)f2b(v.z) | ((unsigned)f2b(v.w) << 16);
    uint2 p; p.x = lo; p.y = hi;
    *(uint2*)(Wb + i) = p;
}

// ---------------- K0b: sc2[k] = scale[k]*sum_c cw[k,c]^2 ; bn1 affine -------
__global__ __launch_bounds__(256) void k_prep(const float* __restrict__ cw,
                                              const float* __restrict__ scale,
                                              const float* __restrict__ g1,
                                              const float* __restrict__ b1,
                                              const float* __restrict__ m1,
                                              const float* __restrict__ v1,
                                              float* __restrict__ sc2,
                                              float* __restrict__ s1,
                                              float* __restrict__ t1) {
    int t = threadIdx.x;
    int k = t >> 3, l8 = t & 7;
    const float* row = cw + k * CC + l8 * 64;
    float s = 0.f;
#pragma unroll
    for (int i = 0; i < 16; i++) {
        float4 c4 = *(const float4*)(row + i * 4);
        s += c4.x * c4.x + c4.y * c4.y + c4.z * c4.z + c4.w * c4.w;
    }
    s += __shfl_xor(s, 1); s += __shfl_xor(s, 2); s += __shfl_xor(s, 4);
    if (l8 == 0) sc2[k] = scale[k] * s;
    if (t < KK) {
        float sv = rsqrtf(v1[t] + EPSF) * g1[t];
        s1[t] = sv;
        t1[t] = b1[t] - m1[t] * sv;
    }
}

// ---------------- K1a: x (B,C,N) fp32 -> xT (B,N,C) bf16 --------------------
__global__ __launch_bounds__(256) void k_transpose(const float* __restrict__ x,
                                                   unsigned short* __restrict__ xT) {
    __shared__ float tile[64][65];
    int bid = blockIdx.x;
    int b   = bid >> 9;
    int rem = bid & 511;
    int c0  = (rem >> 6) * 64;
    int n0  = (rem & 63) * 64;
    int t = threadIdx.x;
#pragma unroll
    for (int p = 0; p < 4; p++) {
        int s = p * 256 + t;
        int row = s >> 4, col = (s & 15) * 4;
        float4 v = *(const float4*)(x + (size_t)(b * CC + c0 + row) * HWN + n0 + col);
        tile[row][col]     = v.x;
        tile[row][col + 1] = v.y;
        tile[row][col + 2] = v.z;
        tile[row][col + 3] = v.w;
    }
    __syncthreads();
    int nr = t >> 2;
    int cg = (t & 3) * 16;
    unsigned u[8];
#pragma unroll
    for (int j = 0; j < 8; j++) {
        u[j] = (unsigned)f2b(tile[cg + 2 * j][nr]) |
               ((unsigned)f2b(tile[cg + 2 * j + 1][nr]) << 16);
    }
    unsigned short* dst = xT + (size_t)(b * HWN + n0 + nr) * CC + c0 + cg;
    uint4 a; a.x = u[0]; a.y = u[1]; a.z = u[2]; a.w = u[3];
    uint4 c; c.x = u[4]; c.y = u[5]; c.z = u[6]; c.w = u[7];
    *(uint4*)(dst)     = a;
    *(uint4*)(dst + 8) = c;
}

// ---------------- K1b: conv GEMM + BN2 + ReLU -> feats bf16, x2 -------------
// feats[b,n,o] = relu(bn2( sum_c xT[b,n,c]*W[o,c] )) ; x2[b,n] = sum_o feats^2
__global__ __launch_bounds__(256) void k_conv_gemm(const unsigned short* __restrict__ xT,
                                                   const unsigned short* __restrict__ Wb,
                                                   const float* __restrict__ g2,
                                                   const float* __restrict__ b2,
                                                   const float* __restrict__ m2,
                                                   const float* __restrict__ v2,
                                                   unsigned short* __restrict__ feats,
                                                   float* __restrict__ x2) {
    __shared__ short As[128 * 32];
    __shared__ short Bs[128 * 32];
    int bid = blockIdx.x;
    int b   = bid >> 7;
    int rem = bid & 127;
    int m0  = (rem >> 2) * 128;   // spatial n base
    int o0  = (rem & 3) * 128;    // out-channel base (fastest -> L3 reuse of xT stripe)
    int t = threadIdx.x, lane = t & 63, wave = t >> 6;
    int mb = (wave >> 1) * 64, ob = (wave & 1) * 64;
    int col_l = lane & 15, quad = lane >> 4;

    f32x4 zero = {0.f, 0.f, 0.f, 0.f};
    f32x4 acc[4][4];
#pragma unroll
    for (int i = 0; i < 4; i++)
#pragma unroll
        for (int j = 0; j < 4; j++) acc[i][j] = zero;

    const unsigned short* Abase = xT + (size_t)(b * HWN + m0) * CC;
    const unsigned short* Bbase = Wb + o0 * CC;

    for (int kc = 0; kc < 16; kc++) {
        int k0 = kc * 32;
#pragma unroll
        for (int p = 0; p < 2; p++) {
            int s = p * 256 + t;
            int row = s >> 2, part = (s & 3) * 8;
            *(uint4*)(&As[row * 32 + part]) = *(const uint4*)(Abase + row * CC + k0 + part);
            *(uint4*)(&Bs[row * 32 + part]) = *(const uint4*)(Bbase + row * CC + k0 + part);
        }
        __syncthreads();
        bf16x8 af[4], bfv[4];
#pragma unroll
        for (int im = 0; im < 4; im++)
            af[im] = *(const bf16x8*)(&As[(mb + im * 16 + col_l) * 32 + quad * 8]);
#pragma unroll
        for (int in = 0; in < 4; in++)
            bfv[in] = *(const bf16x8*)(&Bs[(ob + in * 16 + col_l) * 32 + quad * 8]);
#pragma unroll
        for (int im = 0; im < 4; im++)
#pragma unroll
            for (int in = 0; in < 4; in++)
                acc[im][in] = __builtin_amdgcn_mfma_f32_16x16x32_bf16(af[im], bfv[in],
                                                                     acc[im][in], 0, 0, 0);
        __syncthreads();
    }

    // Epilogue: BN2 + ReLU, store bf16, accumulate x2 per spatial row
    float scv[4], offv[4];
    int oidx[4];
#pragma unroll
    for (int in = 0; in < 4; in++) {
        int o = o0 + ob + in * 16 + col_l;
        oidx[in] = o;
        float sv = rsqrtf(v2[o] + EPSF) * g2[o];
        scv[in]  = sv;
        offv[in] = b2[o] - m2[o] * sv;
    }
#pragma unroll
    for (int im = 0; im < 4; im++) {
#pragma unroll
        for (int r = 0; r < 4; r++) {
            int n = m0 + mb + im * 16 + quad * 4 + r;
            unsigned short* frow = feats + (size_t)(b * HWN + n) * CC;
            float ss = 0.f;
#pragma unroll
            for (int in = 0; in < 4; in++) {
                float v = acc[im][in][r] * scv[in] + offv[in];
                v = fmaxf(v, 0.f);
                frow[oidx[in]] = f2b(v);
                ss += v * v;
            }
            ss += __shfl_xor(ss, 1); ss += __shfl_xor(ss, 2);
            ss += __shfl_xor(ss, 4); ss += __shfl_xor(ss, 8);
            if (col_l == 0) atomicAdd(&x2[b * HWN + n], ss);
        }
    }
}

// ---------------- K2a: xc[b,n,k] = sum_c feats[b,n,c]*cw[k,c] ---------------
__global__ __launch_bounds__(256) void k_xc_gemm(const unsigned short* __restrict__ feats,
                                                 const float* __restrict__ cw,
                                                 float* __restrict__ xc) {
    __shared__ short As[256 * 32];
    __shared__ short Bs[32 * 32];
    int bid = blockIdx.x;
    int b  = bid >> 4;
    int n0 = (bid & 15) * 256;
    int t = threadIdx.x, lane = t & 63, wave = t >> 6;
    int mb = wave * 64;
    int col_l = lane & 15, quad = lane >> 4;

    f32x4 zero = {0.f, 0.f, 0.f, 0.f};
    f32x4 acc[4][2];
#pragma unroll
    for (int i = 0; i < 4; i++) { acc[i][0] = zero; acc[i][1] = zero; }

    const unsigned short* Abase = feats + (size_t)(b * HWN + n0) * CC;

    for (int kc = 0; kc < 16; kc++) {
        int k0 = kc * 32;
#pragma unroll
        for (int p = 0; p < 4; p++) {
            int s = p * 256 + t;
            int row = s >> 2, part = (s & 3) * 8;
            *(uint4*)(&As[row * 32 + part]) = *(const uint4*)(Abase + row * CC + k0 + part);
        }
        {   // cw staging: 32 rows x 32 cols
            int row = t >> 3, c4 = (t & 7) * 4;
            float4 v = *(const float4*)(cw + row * CC + k0 + c4);
            unsigned lo = (unsigned)f2b(v.x) | ((unsigned)f2b(v.y) << 16);
            unsigned hi = (unsigned)f2b(v.z) | ((unsigned)f2b(v.w) << 16);
            uint2 pkd; pkd.x = lo; pkd.y = hi;
            *(uint2*)(&Bs[row * 32 + c4]) = pkd;
        }
        __syncthreads();
        bf16x8 af[4], bfv[2];
#pragma unroll
        for (int im = 0; im < 4; im++)
            af[im] = *(const bf16x8*)(&As[(mb + im * 16 + col_l) * 32 + quad * 8]);
#pragma unroll
        for (int in = 0; in < 2; in++)
            bfv[in] = *(const bf16x8*)(&Bs[(in * 16 + col_l) * 32 + quad * 8]);
#pragma unroll
        for (int im = 0; im < 4; im++)
#pragma unroll
            for (int in = 0; in < 2; in++)
                acc[im][in] = __builtin_amdgcn_mfma_f32_16x16x32_bf16(af[im], bfv[in],
                                                                     acc[im][in], 0, 0, 0);
        __syncthreads();
    }
#pragma unroll
    for (int im = 0; im < 4; im++)
#pragma unroll
        for (int in = 0; in < 2; in++)
#pragma unroll
            for (int r = 0; r < 4; r++) {
                int n = n0 + mb + im * 16 + quad * 4 + r;
                int k = in * 16 + col_l;
                xc[(size_t)(b * HWN + n) * KK + k] = acc[im][in][r];
            }
}

// ---------------- K2b: softmax over k; write assign^T bf16 ------------------
__global__ __launch_bounds__(256) void k_softmax(const float* __restrict__ xc,
                                                 const float* __restrict__ x2,
                                                 const float* __restrict__ scale,
                                                 const float* __restrict__ sc2,
                                                 unsigned short* __restrict__ assignT) {
    __shared__ float sl[KK], cl[KK];
    int t = threadIdx.x;
    if (t < KK) { sl[t] = scale[t]; cl[t] = sc2[t]; }
    __syncthreads();
    int n  = blockIdx.x * 256 + t;
    int b  = n >> 12;
    int nl = n & 4095;
    const float* xr = xc + (size_t)n * KK;
    float x2v = x2[n];
    float d[KK];
#pragma unroll
    for (int k = 0; k < KK; k++)
        d[k] = sl[k] * (x2v - 2.f * xr[k]) + cl[k];
    float m = -3.4e38f;
#pragma unroll
    for (int k = 0; k < KK; k++) m = fmaxf(m, d[k]);
    float s = 0.f;
#pragma unroll
    for (int k = 0; k < KK; k++) { d[k] = __expf(d[k] - m); s += d[k]; }
    float r = 1.f / s;
#pragma unroll
    for (int k = 0; k < KK; k++)
        assignT[(size_t)(b * KK + k) * HWN + nl] = f2b(d[k] * r);
}

// ---------------- K3: encoded GEMM + BN1 + ReLU + mean_k --------------------
// efeat[b,c] = (1/32) sum_k relu( s1[k]*(sum_n w[n,k]*f[n,c] - asum[k]*cw[k,c]) + t1[k] )
__global__ __launch_bounds__(256) void k_encode(const unsigned short* __restrict__ assignT,
                                                const unsigned short* __restrict__ feats,
                                                const float* __restrict__ cw,
                                                const float* __restrict__ s1,
                                                const float* __restrict__ t1,
                                                float* __restrict__ efeat) {
    __shared__ short As[32 * 40];
    __shared__ short Bs[32 * 40];
    __shared__ float asum_l[KK];
    __shared__ float mean_l[KK];
    int bid = blockIdx.x;
    int b  = bid >> 4;
    int c0 = (bid & 15) * 32;
    int t = threadIdx.x, lane = t & 63, wave = t >> 6;
    int im = wave & 1, in = wave >> 1;
    int col_l = lane & 15, quad = lane >> 4;
    if (t < KK) { asum_l[t] = 0.f; mean_l[t] = 0.f; }

    f32x4 acc = {0.f, 0.f, 0.f, 0.f};
    float asp = 0.f;

    for (int it = 0; it < 128; it++) {
        int n0 = it * 32;
        if (t < 128) {
            // Bs: feats^T slice  Bs[c][n], strided u16 gathers (dense per lane-row)
            int c  = t & 31;
            int ng = (t >> 5) * 8;
            unsigned short u[8];
#pragma unroll
            for (int j = 0; j < 8; j++)
                u[j] = feats[(size_t)(b * HWN + n0 + ng + j) * CC + c0 + c];
            uint4 pk;
            pk.x = (unsigned)u[0] | ((unsigned)u[1] << 16);
            pk.y = (unsigned)u[2] | ((unsigned)u[3] << 16);
            pk.z = (unsigned)u[4] | ((unsigned)u[5] << 16);
            pk.w = (unsigned)u[6] | ((unsigned)u[7] << 16);
            *(uint4*)(&Bs[c * 40 + ng]) = pk;
        } else {
            int u2 = t - 128;
            int row = u2 >> 2, part = (u2 & 3) * 8;
            uint4 v = *(const uint4*)(assignT + (size_t)(b * KK + row) * HWN + n0 + part);
            *(uint4*)(&As[row * 40 + part]) = v;
            asp += b2f((unsigned short)(v.x & 0xffff)) + b2f((unsigned short)(v.x >> 16));
            asp += b2f((unsigned short)(v.y & 0xffff)) + b2f((unsigned short)(v.y >> 16));
            asp += b2f((unsigned short)(v.z & 0xffff)) + b2f((unsigned short)(v.z >> 16));
            asp += b2f((unsigned short)(v.w & 0xffff)) + b2f((unsigned short)(v.w >> 16));
        }
        __syncthreads();
        bf16x8 af  = *(const bf16x8*)(&As[(im * 16 + col_l) * 40 + quad * 8]);
        bf16x8 bfv = *(const bf16x8*)(&Bs[(in * 16 + col_l) * 40 + quad * 8]);
        acc = __builtin_amdgcn_mfma_f32_16x16x32_bf16(af, bfv, acc, 0, 0, 0);
        __syncthreads();
    }
    if (t >= 128) atomicAdd(&asum_l[(t - 128) >> 2], asp);
    __syncthreads();

    int c = c0 + in * 16 + col_l;
    float s = 0.f;
#pragma unroll
    for (int r = 0; r < 4; r++) {
        int k = im * 16 + quad * 4 + r;
        float enc = acc[r] - asum_l[k] * cw[k * CC + c];
        float v = enc * s1[k] + t1[k];
        s += fmaxf(v, 0.f);
    }
    s *= (1.f / 32.f);
    s += __shfl_xor(s, 16);
    s += __shfl_xor(s, 32);
    if (lane < 16) atomicAdd(&mean_l[in * 16 + col_l], s);
    __syncthreads();
    if (t < KK) efeat[b * CC + c0 + t] = mean_l[t];
}

// ---------------- K4: gamma = sigmoid(efeat @ fc_w^T + fc_b) ----------------
__global__ __launch_bounds__(256) void k_fc(const float* __restrict__ efeat,
                                            const float* __restrict__ fcw,
                                            const float* __restrict__ fcb,
                                            float* __restrict__ gamma) {
    __shared__ float ef[CC];
    int bid = blockIdx.x;
    int b  = bid >> 1;
    int o0 = (bid & 1) * 256;
    int t = threadIdx.x;
    if (t < 128) *(float4*)(&ef[t * 4]) = *(const float4*)(efeat + b * CC + t * 4);
    __syncthreads();
    int o = o0 + t;
    float a = fcb[o];
    const float* wrow = fcw + (size_t)o * CC;
#pragma unroll 4
    for (int c4 = 0; c4 < 128; c4++) {
        float4 w = *(const float4*)(wrow + c4 * 4);
        float4 e = *(const float4*)(&ef[c4 * 4]);
        a += w.x * e.x + w.y * e.y + w.z * e.z + w.w * e.w;
    }
    gamma[b * CC + o] = 1.f / (1.f + __expf(-a));
}

// ---------------- K5: out = relu(x * (1 + gamma[b,c])) ----------------------
__global__ __launch_bounds__(256) void k_gate(const float* __restrict__ x,
                                              const float* __restrict__ gamma,
                                              float* __restrict__ out) {
    int i = blockIdx.x * 256 + threadIdx.x;
    int idx = i * 4;
    int b = idx >> 21;            // C*H*W = 2^21
    int c = (idx >> 12) & 511;    // H*W   = 2^12
    float g = 1.f + gamma[b * CC + c];
    float4 v = *(const float4*)(x + idx);
    v.x = fmaxf(v.x * g, 0.f);
    v.y = fmaxf(v.y * g, 0.f);
    v.z = fmaxf(v.z * g, 0.f);
    v.w = fmaxf(v.w * g, 0.f);
    *(float4*)(out + idx) = v;
}

extern "C" void kernel_launch(void* const* d_in, const int* in_sizes, int n_in,
                              void* d_out, int out_size, void* d_ws, size_t ws_size,
                              hipStream_t stream) {
    const float* x      = (const float*)d_in[0];
    const float* conv_w = (const float*)d_in[1];
    const float* bn2_g  = (const float*)d_in[2];
    const float* bn2_b  = (const float*)d_in[3];
    const float* bn2_m  = (const float*)d_in[4];
    const float* bn2_v  = (const float*)d_in[5];
    const float* cw     = (const float*)d_in[6];
    const float* scale  = (const float*)d_in[7];
    const float* bn1_g  = (const float*)d_in[8];
    const float* bn1_b  = (const float*)d_in[9];
    const float* bn1_m  = (const float*)d_in[10];
    const float* bn1_v  = (const float*)d_in[11];
    const float* fc_w   = (const float*)d_in[12];
    const float* fc_b   = (const float*)d_in[13];

    float* outf = (float*)d_out;               // [0,8192) efeat, [8192,...) gated output
    char* ws = (char*)d_ws;

    // workspace layout
    unsigned short* feats   = (unsigned short*)(ws);                    // 67,108,864 B
    float*          xc      = (float*)(ws + 67108864);                  //  8,388,608 B
    float*          x2      = (float*)(ws + 75497472);                  //    262,144 B
    unsigned short* assignT = (unsigned short*)(ws + 75759616);         //  4,194,304 B
    unsigned short* Wb      = (unsigned short*)(ws + 79953920);         //    524,288 B
    float*          sc2     = (float*)(ws + 80478208);
    float*          s1      = (float*)(ws + 80478464);
    float*          t1      = (float*)(ws + 80478720);
    float*          gamma   = (float*)(ws + 80478976);                  //     32,768 B

    // x^T bf16 lives in the (not-yet-written) tail of d_out: 67 MB, overwritten by K5 later
    unsigned short* xT = (unsigned short*)(outf + 8192);

    hipMemsetAsync(x2, 0, BB * HWN * sizeof(float), stream);

    k_convert_w<<<256, 256, 0, stream>>>(conv_w, Wb);
    k_prep<<<1, 256, 0, stream>>>(cw, scale, bn1_g, bn1_b, bn1_m, bn1_v, sc2, s1, t1);
    k_transpose<<<8192, 256, 0, stream>>>(x, xT);
    k_conv_gemm<<<2048, 256, 0, stream>>>(xT, Wb, bn2_g, bn2_b, bn2_m, bn2_v, feats, x2);
    k_xc_gemm<<<256, 256, 0, stream>>>(feats, cw, xc);
    k_softmax<<<256, 256, 0, stream>>>(xc, x2, scale, sc2, assignT);
    k_encode<<<256, 256, 0, stream>>>(assignT, feats, cw, s1, t1, outf);
    k_fc<<<32, 256, 0, stream>>>(outf, fc_w, fc_b, gamma);
    k_gate<<<32768, 256, 0, stream>>>(x, gamma, outf + 8192);
}

// Round 2
// 450.642 us; speedup vs baseline: 1.0654x; 1.0654x over previous
//
#include <hip/hip_runtime.h>
#include <hip/hip_bf16.h>

// Problem constants (B, C, H, W, K) = (16, 512, 64, 64, 32)
#define BB   16
#define CC   512
#define HWN  4096        // H*W
#define KK   32
#define EPSF 1e-5f

typedef short bf16x8 __attribute__((ext_vector_type(8)));
typedef float f32x4  __attribute__((ext_vector_type(4)));

#define MFMA16 __builtin_amdgcn_mfma_f32_16x16x32_bf16

// async global->LDS, 16B per lane. LDS dest = wave-uniform base + lane*16.
#define GLD16(g, l) __builtin_amdgcn_global_load_lds(                          \
    (const __attribute__((address_space(1))) void*)(g),                        \
    (__attribute__((address_space(3))) void*)(l), 16, 0, 0)

static __device__ __forceinline__ unsigned short f2b(float f) {
    unsigned u = __builtin_bit_cast(unsigned, f);
    unsigned r = (u + 0x7FFFu + ((u >> 16) & 1u)) >> 16;   // RNE
    return (unsigned short)r;
}

// ---------------- K0: weight conversions + small precomputes ----------------
__global__ __launch_bounds__(256) void k_prep(const float* __restrict__ W,
                                              const float* __restrict__ cw,
                                              const float* __restrict__ scale,
                                              const float* __restrict__ g1,
                                              const float* __restrict__ b1,
                                              const float* __restrict__ m1,
                                              const float* __restrict__ v1,
                                              unsigned short* __restrict__ Wb,
                                              unsigned short* __restrict__ cwb,
                                              float* __restrict__ sc2,
                                              float* __restrict__ s1,
                                              float* __restrict__ t1) {
    int bid = blockIdx.x, t = threadIdx.x;
    if (bid < 256) {                       // conv_w fp32 -> bf16 (262144 elems)
        int i = (bid * 256 + t) * 4;
        float4 v = *(const float4*)(W + i);
        uint2 p;
        p.x = (unsigned)f2b(v.x) | ((unsigned)f2b(v.y) << 16);
        p.y = (unsigned)f2b(v.z) | ((unsigned)f2b(v.w) << 16);
        *(uint2*)(Wb + i) = p;
    } else if (bid < 272) {                // codewords fp32 -> bf16 (16384 elems)
        int i = ((bid - 256) * 256 + t) * 4;
        float4 v = *(const float4*)(cw + i);
        uint2 p;
        p.x = (unsigned)f2b(v.x) | ((unsigned)f2b(v.y) << 16);
        p.y = (unsigned)f2b(v.z) | ((unsigned)f2b(v.w) << 16);
        *(uint2*)(cwb + i) = p;
    } else {                               // sc2[k] = scale*||c_k||^2 ; bn1 affine
        int k = t >> 3, l8 = t & 7;
        const float* row = cw + k * CC + l8 * 64;
        float s = 0.f;
#pragma unroll
        for (int i = 0; i < 16; i++) {
            float4 c4 = *(const float4*)(row + i * 4);
            s += c4.x * c4.x + c4.y * c4.y + c4.z * c4.z + c4.w * c4.w;
        }
        s += __shfl_xor(s, 1); s += __shfl_xor(s, 2); s += __shfl_xor(s, 4);
        if (l8 == 0) sc2[k] = scale[k] * s;
        if (t < KK) {
            float sv = rsqrtf(v1[t] + EPSF) * g1[t];
            s1[t] = sv;
            t1[t] = b1[t] - m1[t] * sv;
        }
    }
}

// ---------------- K1a: x (B,C,N) fp32 -> xT (B,N,C) bf16 --------------------
__global__ __launch_bounds__(256) void k_transpose(const float* __restrict__ x,
                                                   unsigned short* __restrict__ xT) {
    __shared__ float tile[64][65];
    int bid = blockIdx.x;
    int b   = bid >> 9;
    int rem = bid & 511;
    int c0  = (rem >> 6) * 64;
    int n0  = (rem & 63) * 64;
    int t = threadIdx.x;
#pragma unroll
    for (int p = 0; p < 4; p++) {
        int s = p * 256 + t;
        int row = s >> 4, col = (s & 15) * 4;
        float4 v = *(const float4*)(x + (size_t)(b * CC + c0 + row) * HWN + n0 + col);
        tile[row][col]     = v.x;
        tile[row][col + 1] = v.y;
        tile[row][col + 2] = v.z;
        tile[row][col + 3] = v.w;
    }
    __syncthreads();
    int nr = t >> 2;
    int cg = (t & 3) * 16;
    unsigned u[8];
#pragma unroll
    for (int j = 0; j < 8; j++) {
        u[j] = (unsigned)f2b(tile[cg + 2 * j][nr]) |
               ((unsigned)f2b(tile[cg + 2 * j + 1][nr]) << 16);
    }
    unsigned short* dst = xT + (size_t)(b * HWN + n0 + nr) * CC + c0 + cg;
    uint4 a; a.x = u[0]; a.y = u[1]; a.z = u[2]; a.w = u[3];
    uint4 c; c.x = u[4]; c.y = u[5]; c.z = u[6]; c.w = u[7];
    *(uint4*)(dst)     = a;
    *(uint4*)(dst + 8) = c;
}

// ---------------- K1b: conv GEMM + BN2 + ReLU -> feats, featsT, x2 ----------
__global__ __launch_bounds__(256) void k_conv_gemm(const unsigned short* __restrict__ xT,
                                                   const unsigned short* __restrict__ Wb,
                                                   const float* __restrict__ g2,
                                                   const float* __restrict__ b2,
                                                   const float* __restrict__ m2,
                                                   const float* __restrict__ v2,
                                                   unsigned short* __restrict__ feats,
                                                   unsigned short* __restrict__ featsT,
                                                   float* __restrict__ x2) {
    __shared__ short As[128 * 32];
    __shared__ short Bs[128 * 32];
    int bid = blockIdx.x;
    int b   = bid >> 7;
    int rem = bid & 127;
    int m0  = (rem >> 2) * 128;   // spatial n base
    int o0  = (rem & 3) * 128;    // out-channel base fastest -> L2 reuse of xT stripe
    int t = threadIdx.x, lane = t & 63, wave = t >> 6;
    int mb = (wave >> 1) * 64, ob = (wave & 1) * 64;
    int col_l = lane & 15, quad = lane >> 4;

    f32x4 zero = {0.f, 0.f, 0.f, 0.f};
    f32x4 acc[4][4];
#pragma unroll
    for (int i = 0; i < 4; i++)
#pragma unroll
        for (int j = 0; j < 4; j++) acc[i][j] = zero;

    const unsigned short* Abase = xT + (size_t)(b * HWN + m0) * CC;
    const unsigned short* Bbase = Wb + (size_t)o0 * CC;

    for (int kc = 0; kc < 16; kc++) {
        int k0 = kc * 32;
#pragma unroll
        for (int p = 0; p < 2; p++) {
            int sbase = p * 256 + wave * 64;
            int s = sbase + lane;
            const unsigned short* ga = Abase + (size_t)(s >> 2) * CC + k0 + (s & 3) * 8;
            const unsigned short* gb = Bbase + (size_t)(s >> 2) * CC + k0 + (s & 3) * 8;
            GLD16(ga, (char*)As + sbase * 16);
            GLD16(gb, (char*)Bs + sbase * 16);
        }
        __syncthreads();
        bf16x8 af[4], bfv[4];
#pragma unroll
        for (int im = 0; im < 4; im++)
            af[im] = *(const bf16x8*)(&As[(mb + im * 16 + col_l) * 32 + quad * 8]);
#pragma unroll
        for (int in = 0; in < 4; in++)
            bfv[in] = *(const bf16x8*)(&Bs[(ob + in * 16 + col_l) * 32 + quad * 8]);
#pragma unroll
        for (int im = 0; im < 4; im++)
#pragma unroll
            for (int in = 0; in < 4; in++)
                acc[im][in] = MFMA16(af[im], bfv[in], acc[im][in], 0, 0, 0);
        __syncthreads();
    }

    // Epilogue: BN2+ReLU, store feats (n-major) + featsT (c-major), x2
    float scv[4], offv[4];
    int oidx[4];
#pragma unroll
    for (int in = 0; in < 4; in++) {
        int o = o0 + ob + in * 16 + col_l;
        oidx[in] = o;
        float sv = rsqrtf(v2[o] + EPSF) * g2[o];
        scv[in]  = sv;
        offv[in] = b2[o] - m2[o] * sv;
    }
#pragma unroll
    for (int im = 0; im < 4; im++) {
        int nb = m0 + mb + im * 16 + quad * 4;
        float v[4][4];
#pragma unroll
        for (int in = 0; in < 4; in++)
#pragma unroll
            for (int r = 0; r < 4; r++)
                v[in][r] = fmaxf(acc[im][in][r] * scv[in] + offv[in], 0.f);
        // feats (n-major)
#pragma unroll
        for (int r = 0; r < 4; r++) {
            unsigned short* frow = feats + (size_t)(b * HWN + nb + r) * CC;
#pragma unroll
            for (int in = 0; in < 4; in++) frow[oidx[in]] = f2b(v[in][r]);
        }
        // featsT (c-major): 4 consecutive n packed per 8B store
#pragma unroll
        for (int in = 0; in < 4; in++) {
            uint2 pk;
            pk.x = (unsigned)f2b(v[in][0]) | ((unsigned)f2b(v[in][1]) << 16);
            pk.y = (unsigned)f2b(v[in][2]) | ((unsigned)f2b(v[in][3]) << 16);
            *(uint2*)(featsT + (size_t)(b * CC + oidx[in]) * HWN + nb) = pk;
        }
        // x2 partial (sum over this block's 128 o-channels)
#pragma unroll
        for (int r = 0; r < 4; r++) {
            float ss = v[0][r] * v[0][r] + v[1][r] * v[1][r] +
                       v[2][r] * v[2][r] + v[3][r] * v[3][r];
            ss += __shfl_xor(ss, 1); ss += __shfl_xor(ss, 2);
            ss += __shfl_xor(ss, 4); ss += __shfl_xor(ss, 8);
            if (col_l == 0) atomicAdd(&x2[b * HWN + nb + r], ss);
        }
    }
}

// ---------------- K2: fused xc^T GEMM + softmax -> assignT bf16, asum -------
// xcT[k,n] = sum_c cw[k,c] feats[n,c]; dist = scale*(x2 - 2 xc) + sc2; softmax_k
__global__ __launch_bounds__(256) void k_assign(const unsigned short* __restrict__ feats,
                                                const unsigned short* __restrict__ cwb,
                                                const float* __restrict__ x2,
                                                const float* __restrict__ scale,
                                                const float* __restrict__ sc2,
                                                unsigned short* __restrict__ assignT,
                                                float* __restrict__ asum) {
    __shared__ short cwl[32 * 520];      // padded: stride 520 shorts (1040B, +4 words mod 32)
    __shared__ short fl[256 * 32];
    __shared__ float sl[KK], cl[KK];
    int bid = blockIdx.x;
    int b = bid >> 4, n0 = (bid & 15) * 256;
    int t = threadIdx.x, lane = t & 63, wave = t >> 6;
    int col_l = lane & 15, quad = lane >> 4;

    // stage all of cw (bf16, 32x512) into padded LDS once
#pragma unroll
    for (int p = 0; p < 8; p++) {
        int s = p * 256 + t;             // 2048 chunks of 8 shorts
        int row = s >> 6, c8 = (s & 63) * 8;
        *(uint4*)(&cwl[row * 520 + c8]) = *(const uint4*)(cwb + row * 512 + c8);
    }
    if (t < KK) { sl[t] = scale[t]; cl[t] = sc2[t]; }

    f32x4 zero = {0.f, 0.f, 0.f, 0.f};
    f32x4 acc[2][4];                     // [k-tile mk][n col-tile ct]
#pragma unroll
    for (int i = 0; i < 2; i++)
#pragma unroll
        for (int j = 0; j < 4; j++) acc[i][j] = zero;

    const unsigned short* Fbase = feats + (size_t)(b * HWN + n0) * CC;
    for (int ci = 0; ci < 16; ci++) {
        int c0 = ci * 32;
#pragma unroll
        for (int p = 0; p < 4; p++) {    // 256 rows x 32c = 16KB = 4 issues
            int sbase = p * 256 + wave * 64;
            int s = sbase + lane;
            const unsigned short* gp = Fbase + (size_t)(s >> 2) * CC + c0 + (s & 3) * 8;
            GLD16(gp, (char*)fl + sbase * 16);
        }
        __syncthreads();
        bf16x8 af0 = *(const bf16x8*)(&cwl[(col_l) * 520 + c0 + quad * 8]);
        bf16x8 af1 = *(const bf16x8*)(&cwl[(16 + col_l) * 520 + c0 + quad * 8]);
#pragma unroll
        for (int ct = 0; ct < 4; ct++) {
            bf16x8 bf = *(const bf16x8*)(&fl[(wave * 64 + ct * 16 + col_l) * 32 + quad * 8]);
            acc[0][ct] = MFMA16(af0, bf, acc[0][ct], 0, 0, 0);
            acc[1][ct] = MFMA16(af1, bf, acc[1][ct], 0, 0, 0);
        }
        __syncthreads();
    }

    // softmax over k per n column; write assignT; accumulate asum
    float asw[2][4];
#pragma unroll
    for (int mk = 0; mk < 2; mk++)
#pragma unroll
        for (int r = 0; r < 4; r++) asw[mk][r] = 0.f;

#pragma unroll
    for (int ct = 0; ct < 4; ct++) {
        int n = n0 + wave * 64 + ct * 16 + col_l;
        float x2v = x2[b * HWN + n];
        float d[2][4];
        float mmax = -3.4e38f;
#pragma unroll
        for (int mk = 0; mk < 2; mk++)
#pragma unroll
            for (int r = 0; r < 4; r++) {
                int k = mk * 16 + quad * 4 + r;
                d[mk][r] = sl[k] * (x2v - 2.f * acc[mk][ct][r]) + cl[k];
                mmax = fmaxf(mmax, d[mk][r]);
            }
        mmax = fmaxf(mmax, __shfl_xor(mmax, 16));
        mmax = fmaxf(mmax, __shfl_xor(mmax, 32));
        float ssum = 0.f;
#pragma unroll
        for (int mk = 0; mk < 2; mk++)
#pragma unroll
            for (int r = 0; r < 4; r++) {
                d[mk][r] = __expf(d[mk][r] - mmax);
                ssum += d[mk][r];
            }
        ssum += __shfl_xor(ssum, 16);
        ssum += __shfl_xor(ssum, 32);
        float rinv = 1.f / ssum;
#pragma unroll
        for (int mk = 0; mk < 2; mk++)
#pragma unroll
            for (int r = 0; r < 4; r++) {
                int k = mk * 16 + quad * 4 + r;
                float a = d[mk][r] * rinv;
                assignT[(size_t)(b * KK + k) * HWN + n] = f2b(a);
                float p = a;
                p += __shfl_xor(p, 1); p += __shfl_xor(p, 2);
                p += __shfl_xor(p, 4); p += __shfl_xor(p, 8);
                asw[mk][r] += p;       // valid on col_l==0 lanes
            }
    }
#pragma unroll
    for (int mk = 0; mk < 2; mk++)
#pragma unroll
        for (int r = 0; r < 4; r++)
            if (col_l == 0)
                atomicAdd(&asum[b * KK + mk * 16 + quad * 4 + r], asw[mk][r]);
}

// ---------------- K3: encode GEMM: enc[b,c,k] += sum_n a[k,n] fT[c,n] -------
__global__ __launch_bounds__(256) void k_encode(const unsigned short* __restrict__ featsT,
                                                const unsigned short* __restrict__ assignT,
                                                float* __restrict__ enc) {
    __shared__ short Al[128 * 32];
    __shared__ short Bl[32 * 32];
    int bid = blockIdx.x;
    int b   = bid >> 5;
    int rem = bid & 31;
    int c0  = (rem >> 3) * 128;
    int ns  = rem & 7;                   // n-split: [ns*512, ns*512+512)
    int t = threadIdx.x, lane = t & 63, wave = t >> 6;
    int col_l = lane & 15, quad = lane >> 4;

    f32x4 zero = {0.f, 0.f, 0.f, 0.f};
    f32x4 acc[2][2];                     // [c-subtile][k col-tile]
    acc[0][0] = zero; acc[0][1] = zero; acc[1][0] = zero; acc[1][1] = zero;

    const unsigned short* Abase = featsT + (size_t)(b * CC + c0) * HWN;
    const unsigned short* Bbase = assignT + (size_t)(b * KK) * HWN;

    for (int it = 0; it < 16; it++) {
        int n0 = ns * 512 + it * 32;
#pragma unroll
        for (int p = 0; p < 2; p++) {    // A: 128c x 32n
            int sbase = p * 256 + wave * 64;
            int s = sbase + lane;
            const unsigned short* gp = Abase + (size_t)(s >> 2) * HWN + n0 + (s & 3) * 8;
            GLD16(gp, (char*)Al + sbase * 16);
        }
        if (wave < 2) {                  // B: 32k x 32n
            int sbase = wave * 64;
            int s = sbase + lane;
            const unsigned short* gp = Bbase + (size_t)(s >> 2) * HWN + n0 + (s & 3) * 8;
            GLD16(gp, (char*)Bl + sbase * 16);
        }
        __syncthreads();
        bf16x8 a0 = *(const bf16x8*)(&Al[(wave * 32 + col_l) * 32 + quad * 8]);
        bf16x8 a1 = *(const bf16x8*)(&Al[(wave * 32 + 16 + col_l) * 32 + quad * 8]);
        bf16x8 b0 = *(const bf16x8*)(&Bl[(col_l) * 32 + quad * 8]);
        bf16x8 b1 = *(const bf16x8*)(&Bl[(16 + col_l) * 32 + quad * 8]);
        acc[0][0] = MFMA16(a0, b0, acc[0][0], 0, 0, 0);
        acc[0][1] = MFMA16(a0, b1, acc[0][1], 0, 0, 0);
        acc[1][0] = MFMA16(a1, b0, acc[1][0], 0, 0, 0);
        acc[1][1] = MFMA16(a1, b1, acc[1][1], 0, 0, 0);
        __syncthreads();
    }
#pragma unroll
    for (int i2 = 0; i2 < 2; i2++)
#pragma unroll
        for (int ck = 0; ck < 2; ck++)
#pragma unroll
            for (int r = 0; r < 4; r++) {
                int c = c0 + wave * 32 + i2 * 16 + quad * 4 + r;
                int k = ck * 16 + col_l;
                atomicAdd(&enc[(size_t)(b * CC + c) * KK + k], acc[i2][ck][r]);
            }
}

// ---------------- K3b: BN1 + ReLU + mean over k -> efeat --------------------
__global__ __launch_bounds__(256) void k_efeat(const float* __restrict__ enc,
                                               const float* __restrict__ asum,
                                               const float* __restrict__ cwf,
                                               const float* __restrict__ s1,
                                               const float* __restrict__ t1,
                                               float* __restrict__ efeat) {
    __shared__ float asl[KK], s1l[KK], t1l[KK];
    int b = blockIdx.x, t = threadIdx.x;
    if (t < KK) { asl[t] = asum[b * KK + t]; s1l[t] = s1[t]; t1l[t] = t1[t]; }
    __syncthreads();
#pragma unroll
    for (int cc = 0; cc < 2; cc++) {
        int c = cc * 256 + t;
        const float* er = enc + (size_t)(b * CC + c) * KK;
        float s = 0.f;
#pragma unroll
        for (int k = 0; k < KK; k++) {
            float v = (er[k] - asl[k] * cwf[k * CC + c]) * s1l[k] + t1l[k];
            s += fmaxf(v, 0.f);
        }
        efeat[b * CC + c] = s * (1.f / 32.f);
    }
}

// ---------------- K4: gamma = sigmoid(efeat @ fc_w^T + fc_b) ----------------
__global__ __launch_bounds__(256) void k_fc(const float* __restrict__ efeat,
                                            const float* __restrict__ fcw,
                                            const float* __restrict__ fcb,
                                            float* __restrict__ gamma) {
    __shared__ float ef[CC];
    int bid = blockIdx.x;
    int b  = bid >> 1;
    int o0 = (bid & 1) * 256;
    int t = threadIdx.x;
    if (t < 128) *(float4*)(&ef[t * 4]) = *(const float4*)(efeat + b * CC + t * 4);
    __syncthreads();
    int o = o0 + t;
    float a = fcb[o];
    const float* wrow = fcw + (size_t)o * CC;
#pragma unroll 4
    for (int c4 = 0; c4 < 128; c4++) {
        float4 w = *(const float4*)(wrow + c4 * 4);
        float4 e = *(const float4*)(&ef[c4 * 4]);
        a += w.x * e.x + w.y * e.y + w.z * e.z + w.w * e.w;
    }
    gamma[b * CC + o] = 1.f / (1.f + __expf(-a));
}

// ---------------- K5: out = relu(x * (1 + gamma[b,c])) ----------------------
__global__ __launch_bounds__(256) void k_gate(const float* __restrict__ x,
                                              const float* __restrict__ gamma,
                                              float* __restrict__ out) {
    int i = blockIdx.x * 256 + threadIdx.x;
    int idx = i * 4;
    int b = idx >> 21;            // C*H*W = 2^21
    int c = (idx >> 12) & 511;    // H*W   = 2^12
    float g = 1.f + gamma[b * CC + c];
    float4 v = *(const float4*)(x + idx);
    v.x = fmaxf(v.x * g, 0.f);
    v.y = fmaxf(v.y * g, 0.f);
    v.z = fmaxf(v.z * g, 0.f);
    v.w = fmaxf(v.w * g, 0.f);
    *(float4*)(out + idx) = v;
}

extern "C" void kernel_launch(void* const* d_in, const int* in_sizes, int n_in,
                              void* d_out, int out_size, void* d_ws, size_t ws_size,
                              hipStream_t stream) {
    const float* x      = (const float*)d_in[0];
    const float* conv_w = (const float*)d_in[1];
    const float* bn2_g  = (const float*)d_in[2];
    const float* bn2_b  = (const float*)d_in[3];
    const float* bn2_m  = (const float*)d_in[4];
    const float* bn2_v  = (const float*)d_in[5];
    const float* cw     = (const float*)d_in[6];
    const float* scale  = (const float*)d_in[7];
    const float* bn1_g  = (const float*)d_in[8];
    const float* bn1_b  = (const float*)d_in[9];
    const float* bn1_m  = (const float*)d_in[10];
    const float* bn1_v  = (const float*)d_in[11];
    const float* fc_w   = (const float*)d_in[12];
    const float* fc_b   = (const float*)d_in[13];

    float* outf = (float*)d_out;               // [0,8192) efeat, [8192,...) gated output
    char* ws = (char*)d_ws;

    // workspace layout (x2/asum/enc contiguous -> one memset)
    unsigned short* feats   = (unsigned short*)(ws);                    // 67,108,864
    unsigned short* assignT = (unsigned short*)(ws + 67108864);         //  4,194,304
    unsigned short* Wb      = (unsigned short*)(ws + 71303168);         //    524,288
    unsigned short* cwb     = (unsigned short*)(ws + 71827456);         //     32,768
    float*          x2      = (float*)(ws + 71860224);                  //    262,144
    float*          asum    = (float*)(ws + 72122368);                  //      2,048
    float*          enc     = (float*)(ws + 72124416);                  //  1,048,576
    float*          sc2     = (float*)(ws + 73172992);
    float*          s1      = (float*)(ws + 73173248);
    float*          t1      = (float*)(ws + 73173504);
    float*          gamma   = (float*)(ws + 73173760);                  //     32,768

    // xT and featsT live in d_out's output region, overwritten later by k_gate
    unsigned short* xT     = (unsigned short*)((char*)d_out + 32768);     // 67,108,864
    unsigned short* featsT = (unsigned short*)((char*)d_out + 67141632);  // 67,108,864

    hipMemsetAsync(x2, 0, 262144 + 2048 + 1048576, stream);   // x2 + asum + enc

    k_prep<<<273, 256, 0, stream>>>(conv_w, cw, scale, bn1_g, bn1_b, bn1_m, bn1_v,
                                    Wb, cwb, sc2, s1, t1);
    k_transpose<<<8192, 256, 0, stream>>>(x, xT);
    k_conv_gemm<<<2048, 256, 0, stream>>>(xT, Wb, bn2_g, bn2_b, bn2_m, bn2_v,
                                          feats, featsT, x2);
    k_assign<<<256, 256, 0, stream>>>(feats, cwb, x2, scale, sc2, assignT, asum);
    k_encode<<<512, 256, 0, stream>>>(featsT, assignT, enc);
    k_efeat<<<16, 256, 0, stream>>>(enc, asum, cw, s1, t1, outf);
    k_fc<<<32, 256, 0, stream>>>(outf, fc_w, fc_b, gamma);
    k_gate<<<32768, 256, 0, stream>>>(x, gamma, outf + 8192);
}

// Round 3
// 442.706 us; speedup vs baseline: 1.0845x; 1.0179x over previous
//
#include <hip/hip_runtime.h>
#include <hip/hip_bf16.h>

// Problem constants (B, C, H, W, K) = (16, 512, 64, 64, 32)
#define BB   16
#define CC   512
#define HWN  4096        // H*W
#define KK   32
#define EPSF 1e-5f

typedef short bf16x8 __attribute__((ext_vector_type(8)));
typedef float f32x4  __attribute__((ext_vector_type(4)));

#define MFMA16 __builtin_amdgcn_mfma_f32_16x16x32_bf16

// async global->LDS, 16B per lane. LDS dest = wave-uniform base + lane*16.
#define GLD16(g, l) __builtin_amdgcn_global_load_lds(                          \
    (const __attribute__((address_space(1))) void*)(g),                        \
    (__attribute__((address_space(3))) void*)(l), 16, 0, 0)

// conv epilogue LDS tile addressing: [o][n] stride 136 shorts, 8-short chunks
// XOR-swizzled by (o>>3) so column sweeps spread across banks.
#define EADDR(o, n) ((o) * 136 + (((((n) >> 3) ^ (((o) >> 3) & 15))) << 3) + ((n) & 7))

static __device__ __forceinline__ unsigned short f2b(float f) {
    unsigned u = __builtin_bit_cast(unsigned, f);
    unsigned r = (u + 0x7FFFu + ((u >> 16) & 1u)) >> 16;   // RNE
    return (unsigned short)r;
}

// ---------------- K0: weight conversions + small precomputes ----------------
__global__ __launch_bounds__(256) void k_prep(const float* __restrict__ W,
                                              const float* __restrict__ cw,
                                              const float* __restrict__ scale,
                                              const float* __restrict__ g1,
                                              const float* __restrict__ b1,
                                              const float* __restrict__ m1,
                                              const float* __restrict__ v1,
                                              unsigned short* __restrict__ Wb,
                                              unsigned short* __restrict__ cwb,
                                              float* __restrict__ sc2,
                                              float* __restrict__ s1,
                                              float* __restrict__ t1) {
    int bid = blockIdx.x, t = threadIdx.x;
    if (bid < 256) {                       // conv_w fp32 -> bf16 (262144 elems)
        int i = (bid * 256 + t) * 4;
        float4 v = *(const float4*)(W + i);
        uint2 p;
        p.x = (unsigned)f2b(v.x) | ((unsigned)f2b(v.y) << 16);
        p.y = (unsigned)f2b(v.z) | ((unsigned)f2b(v.w) << 16);
        *(uint2*)(Wb + i) = p;
    } else if (bid < 272) {                // codewords fp32 -> bf16 (16384 elems)
        int i = ((bid - 256) * 256 + t) * 4;
        float4 v = *(const float4*)(cw + i);
        uint2 p;
        p.x = (unsigned)f2b(v.x) | ((unsigned)f2b(v.y) << 16);
        p.y = (unsigned)f2b(v.z) | ((unsigned)f2b(v.w) << 16);
        *(uint2*)(cwb + i) = p;
    } else {                               // sc2[k] = scale*||c_k||^2 ; bn1 affine
        int k = t >> 3, l8 = t & 7;
        const float* row = cw + k * CC + l8 * 64;
        float s = 0.f;
#pragma unroll
        for (int i = 0; i < 16; i++) {
            float4 c4 = *(const float4*)(row + i * 4);
            s += c4.x * c4.x + c4.y * c4.y + c4.z * c4.z + c4.w * c4.w;
        }
        s += __shfl_xor(s, 1); s += __shfl_xor(s, 2); s += __shfl_xor(s, 4);
        if (l8 == 0) sc2[k] = scale[k] * s;
        if (t < KK) {
            float sv = rsqrtf(v1[t] + EPSF) * g1[t];
            s1[t] = sv;
            t1[t] = b1[t] - m1[t] * sv;
        }
    }
}

// ---------------- K1a: x (B,C,N) fp32 -> xT (B,N,C) bf16 --------------------
__global__ __launch_bounds__(256) void k_transpose(const float* __restrict__ x,
                                                   unsigned short* __restrict__ xT) {
    __shared__ float tile[64][65];
    int bid = blockIdx.x;
    int b   = bid >> 9;
    int rem = bid & 511;
    int c0  = (rem >> 6) * 64;
    int n0  = (rem & 63) * 64;
    int t = threadIdx.x;
#pragma unroll
    for (int p = 0; p < 4; p++) {
        int s = p * 256 + t;
        int row = s >> 4, col = (s & 15) * 4;
        float4 v = *(const float4*)(x + (size_t)(b * CC + c0 + row) * HWN + n0 + col);
        tile[row][col]     = v.x;
        tile[row][col + 1] = v.y;
        tile[row][col + 2] = v.z;
        tile[row][col + 3] = v.w;
    }
    __syncthreads();
    int nr = t >> 2;
    int cg = (t & 3) * 16;
    unsigned u[8];
#pragma unroll
    for (int j = 0; j < 8; j++) {
        u[j] = (unsigned)f2b(tile[cg + 2 * j][nr]) |
               ((unsigned)f2b(tile[cg + 2 * j + 1][nr]) << 16);
    }
    unsigned short* dst = xT + (size_t)(b * HWN + n0 + nr) * CC + c0 + cg;
    uint4 a; a.x = u[0]; a.y = u[1]; a.z = u[2]; a.w = u[3];
    uint4 c; c.x = u[4]; c.y = u[5]; c.z = u[6]; c.w = u[7];
    *(uint4*)(dst)     = a;
    *(uint4*)(dst + 8) = c;
}

// ---------------- K1b: conv GEMM + BN2 + ReLU -> feats, featsT, x2 ----------
__global__ __launch_bounds__(256) void k_conv_gemm(const unsigned short* __restrict__ xT,
                                                   const unsigned short* __restrict__ Wb,
                                                   const float* __restrict__ g2,
                                                   const float* __restrict__ b2,
                                                   const float* __restrict__ m2,
                                                   const float* __restrict__ v2,
                                                   unsigned short* __restrict__ feats,
                                                   unsigned short* __restrict__ featsT,
                                                   float* __restrict__ x2) {
    // union LDS: staging (A panels @0,8KB; B panels @16KB,24KB = 32KB)
    //            epilogue tile 128x136 shorts = 34,816B
    __shared__ __align__(16) short lds[17408];
    int bid = blockIdx.x;
    int b   = bid >> 7;
    int rem = bid & 127;
    int m0  = (rem >> 2) * 128;   // spatial n base
    int o0  = (rem & 3) * 128;    // out-channel base fastest -> L2 reuse of xT stripe
    int t = threadIdx.x, lane = t & 63, wave = t >> 6;
    int mb = (wave >> 1) * 64, ob = (wave & 1) * 64;
    int col_l = lane & 15, quad = lane >> 4;

    f32x4 zero = {0.f, 0.f, 0.f, 0.f};
    f32x4 acc[4][4];
#pragma unroll
    for (int i = 0; i < 4; i++)
#pragma unroll
        for (int j = 0; j < 4; j++) acc[i][j] = zero;

    const unsigned short* Abase = xT + (size_t)(b * HWN + m0) * CC;
    const unsigned short* Bbase = Wb + (size_t)o0 * CC;

    for (int kc = 0; kc < 8; kc++) {      // BK=64, two 32-wide panels per iter
        int c0 = kc * 64;
#pragma unroll
        for (int pc = 0; pc < 2; pc++) {
#pragma unroll
            for (int p = 0; p < 2; p++) {
                int sbase = p * 256 + wave * 64;
                int s = sbase + lane;
                int row = s >> 2, part = (s & 3) * 8;
                GLD16(Abase + (size_t)row * CC + c0 + pc * 32 + part,
                      (char*)lds + pc * 8192 + sbase * 16);
                GLD16(Bbase + (size_t)row * CC + c0 + pc * 32 + part,
                      (char*)lds + 16384 + pc * 8192 + sbase * 16);
            }
        }
        __syncthreads();
#pragma unroll
        for (int pc = 0; pc < 2; pc++) {
            bf16x8 af[4], bfv[4];
#pragma unroll
            for (int im = 0; im < 4; im++)
                af[im] = *(const bf16x8*)(&lds[pc * 4096 + (mb + im * 16 + col_l) * 32 + quad * 8]);
#pragma unroll
            for (int in = 0; in < 4; in++)
                bfv[in] = *(const bf16x8*)(&lds[8192 + pc * 4096 + (ob + in * 16 + col_l) * 32 + quad * 8]);
#pragma unroll
            for (int im = 0; im < 4; im++)
#pragma unroll
                for (int in = 0; in < 4; in++)
                    acc[im][in] = MFMA16(af[im], bfv[in], acc[im][in], 0, 0, 0);
        }
        __syncthreads();
    }

    // ---- Epilogue: BN2+ReLU; scatter to LDS tile; x2 from registers ----
    float scv[4], offv[4];
#pragma unroll
    for (int in = 0; in < 4; in++) {
        int o = o0 + ob + in * 16 + col_l;
        float sv = rsqrtf(v2[o] + EPSF) * g2[o];
        scv[in]  = sv;
        offv[in] = b2[o] - m2[o] * sv;
    }
#pragma unroll
    for (int im = 0; im < 4; im++) {
        int n_l = mb + im * 16 + quad * 4;
        float vv[4][4];
#pragma unroll
        for (int in = 0; in < 4; in++)
#pragma unroll
            for (int r = 0; r < 4; r++)
                vv[in][r] = fmaxf(acc[im][in][r] * scv[in] + offv[in], 0.f);
#pragma unroll
        for (int in = 0; in < 4; in++) {
            int o_l = ob + in * 16 + col_l;
            uint2 pk;
            pk.x = (unsigned)f2b(vv[in][0]) | ((unsigned)f2b(vv[in][1]) << 16);
            pk.y = (unsigned)f2b(vv[in][2]) | ((unsigned)f2b(vv[in][3]) << 16);
            *(uint2*)(&lds[EADDR(o_l, n_l)]) = pk;
        }
#pragma unroll
        for (int r = 0; r < 4; r++) {
            float ss = vv[0][r] * vv[0][r] + vv[1][r] * vv[1][r] +
                       vv[2][r] * vv[2][r] + vv[3][r] * vv[3][r];
            ss += __shfl_xor(ss, 1); ss += __shfl_xor(ss, 2);
            ss += __shfl_xor(ss, 4); ss += __shfl_xor(ss, 8);
            if (col_l == 0) atomicAdd(&x2[b * HWN + m0 + n_l + r], ss);
        }
    }
    __syncthreads();

    // ---- featsT sweep: coalesced 256B rows (o-major) ----
#pragma unroll
    for (int rr = 0; rr < 8; rr++) {
        int o = rr * 16 + (t >> 4);
        int n16 = t & 15;
        uint4 v = *(const uint4*)(&lds[EADDR(o, n16 * 8)]);
        *(uint4*)(featsT + (size_t)(b * CC + o0 + o) * HWN + m0 + n16 * 8) = v;
    }
    // ---- feats sweep: coalesced 256B rows (n-major) ----
#pragma unroll
    for (int rr = 0; rr < 8; rr++) {
        int n = rr * 16 + (t >> 4);
        int o16 = t & 15;
        unsigned u[4];
#pragma unroll
        for (int jj = 0; jj < 4; jj++) {
            unsigned short a = lds[EADDR(o16 * 8 + 2 * jj,     n)];
            unsigned short bsh = lds[EADDR(o16 * 8 + 2 * jj + 1, n)];
            u[jj] = (unsigned)a | ((unsigned)bsh << 16);
        }
        uint4 pk; pk.x = u[0]; pk.y = u[1]; pk.z = u[2]; pk.w = u[3];
        *(uint4*)(feats + (size_t)(b * HWN + m0 + n) * CC + o0 + o16 * 8) = pk;
    }
}

// ---------------- K2: fused xc^T GEMM + softmax -> assignT bf16, asum -------
__global__ __launch_bounds__(256) void k_assign(const unsigned short* __restrict__ feats,
                                                const unsigned short* __restrict__ cwb,
                                                const float* __restrict__ x2,
                                                const float* __restrict__ scale,
                                                const float* __restrict__ sc2,
                                                unsigned short* __restrict__ assignT,
                                                float* __restrict__ asum) {
    __shared__ short cwl[32 * 520];      // padded bf16 codewords
    __shared__ short fl[128 * 32];
    __shared__ float sl[KK], cl[KK];
    int bid = blockIdx.x;
    int b = bid >> 5, n0 = (bid & 31) * 128;
    int t = threadIdx.x, lane = t & 63, wave = t >> 6;
    int col_l = lane & 15, quad = lane >> 4;

    // stage all of cw (bf16, 32x512) into padded LDS once
#pragma unroll
    for (int p = 0; p < 8; p++) {
        int s = p * 256 + t;             // 2048 chunks of 8 shorts
        int row = s >> 6, c8 = (s & 63) * 8;
        *(uint4*)(&cwl[row * 520 + c8]) = *(const uint4*)(cwb + row * 512 + c8);
    }
    if (t < KK) { sl[t] = scale[t]; cl[t] = sc2[t]; }

    f32x4 zero = {0.f, 0.f, 0.f, 0.f};
    f32x4 acc[2][2];                     // [k-tile mk][n col-tile ct]
    acc[0][0] = zero; acc[0][1] = zero; acc[1][0] = zero; acc[1][1] = zero;

    const unsigned short* Fbase = feats + (size_t)(b * HWN + n0) * CC;
    for (int ci = 0; ci < 16; ci++) {
        int c0 = ci * 32;
#pragma unroll
        for (int p = 0; p < 2; p++) {    // 128 rows x 32c = 8KB
            int sbase = p * 256 + wave * 64;
            int s = sbase + lane;
            GLD16(Fbase + (size_t)(s >> 2) * CC + c0 + (s & 3) * 8,
                  (char*)fl + sbase * 16);
        }
        __syncthreads();
        bf16x8 af0 = *(const bf16x8*)(&cwl[(col_l) * 520 + c0 + quad * 8]);
        bf16x8 af1 = *(const bf16x8*)(&cwl[(16 + col_l) * 520 + c0 + quad * 8]);
#pragma unroll
        for (int ct = 0; ct < 2; ct++) {
            bf16x8 bf = *(const bf16x8*)(&fl[(wave * 32 + ct * 16 + col_l) * 32 + quad * 8]);
            acc[0][ct] = MFMA16(af0, bf, acc[0][ct], 0, 0, 0);
            acc[1][ct] = MFMA16(af1, bf, acc[1][ct], 0, 0, 0);
        }
        __syncthreads();
    }

    // softmax over k per n column; write assignT; accumulate asum
    float asw[2][4];
#pragma unroll
    for (int mk = 0; mk < 2; mk++)
#pragma unroll
        for (int r = 0; r < 4; r++) asw[mk][r] = 0.f;

#pragma unroll
    for (int ct = 0; ct < 2; ct++) {
        int n = n0 + wave * 32 + ct * 16 + col_l;
        float x2v = x2[b * HWN + n];
        float d[2][4];
        float mmax = -3.4e38f;
#pragma unroll
        for (int mk = 0; mk < 2; mk++)
#pragma unroll
            for (int r = 0; r < 4; r++) {
                int k = mk * 16 + quad * 4 + r;
                d[mk][r] = sl[k] * (x2v - 2.f * acc[mk][ct][r]) + cl[k];
                mmax = fmaxf(mmax, d[mk][r]);
            }
        mmax = fmaxf(mmax, __shfl_xor(mmax, 16));
        mmax = fmaxf(mmax, __shfl_xor(mmax, 32));
        float ssum = 0.f;
#pragma unroll
        for (int mk = 0; mk < 2; mk++)
#pragma unroll
            for (int r = 0; r < 4; r++) {
                d[mk][r] = __expf(d[mk][r] - mmax);
                ssum += d[mk][r];
            }
        ssum += __shfl_xor(ssum, 16);
        ssum += __shfl_xor(ssum, 32);
        float rinv = 1.f / ssum;
#pragma unroll
        for (int mk = 0; mk < 2; mk++)
#pragma unroll
            for (int r = 0; r < 4; r++) {
                int k = mk * 16 + quad * 4 + r;
                float a = d[mk][r] * rinv;
                assignT[(size_t)(b * KK + k) * HWN + n] = f2b(a);
                float p = a;
                p += __shfl_xor(p, 1); p += __shfl_xor(p, 2);
                p += __shfl_xor(p, 4); p += __shfl_xor(p, 8);
                asw[mk][r] += p;       // valid on col_l==0 lanes
            }
    }
#pragma unroll
    for (int mk = 0; mk < 2; mk++)
#pragma unroll
        for (int r = 0; r < 4; r++)
            if (col_l == 0)
                atomicAdd(&asum[b * KK + mk * 16 + quad * 4 + r], asw[mk][r]);
}

// ---------------- K3: encode GEMM: enc[b,c,k] += sum_n a[k,n] fT[c,n] -------
__global__ __launch_bounds__(256) void k_encode(const unsigned short* __restrict__ featsT,
                                                const unsigned short* __restrict__ assignT,
                                                float* __restrict__ enc) {
    __shared__ short Al[2][128 * 32];    // 2 n-panels of featsT (c x n)
    __shared__ short Bl[2][32 * 32];     // 2 n-panels of assignT (k x n)
    int bid = blockIdx.x;
    int b   = bid >> 5;
    int rem = bid & 31;
    int c0  = (rem >> 3) * 128;
    int ns  = rem & 7;                   // n-split: [ns*512, ns*512+512)
    int t = threadIdx.x, lane = t & 63, wave = t >> 6;
    int col_l = lane & 15, quad = lane >> 4;

    f32x4 zero = {0.f, 0.f, 0.f, 0.f};
    f32x4 acc[2][2];                     // [c-subtile][k col-tile]
    acc[0][0] = zero; acc[0][1] = zero; acc[1][0] = zero; acc[1][1] = zero;

    const unsigned short* Abase = featsT + (size_t)(b * CC + c0) * HWN;
    const unsigned short* Bbase = assignT + (size_t)(b * KK) * HWN;

    for (int it = 0; it < 8; it++) {     // BK=64 via 2 panels
        int n0 = ns * 512 + it * 64;
#pragma unroll
        for (int pc = 0; pc < 2; pc++) {
#pragma unroll
            for (int p = 0; p < 2; p++) {
                int sbase = p * 256 + wave * 64;
                int s = sbase + lane;
                GLD16(Abase + (size_t)(s >> 2) * HWN + n0 + pc * 32 + (s & 3) * 8,
                      (char*)Al[pc] + sbase * 16);
            }
        }
        {   // B: 2 panels x 2KB = 256 chunks, 1 per thread
            int s = t;
            int pan = s >> 7, row = (s & 127) >> 2, part = (s & 3) * 8;
            GLD16(Bbase + (size_t)row * HWN + n0 + pan * 32 + part,
                  (char*)Bl[0] + ((wave >> 1) * 2048 + (wave & 1) * 1024) + lane * 16);
            (void)pan;
        }
        __syncthreads();
#pragma unroll
        for (int pc = 0; pc < 2; pc++) {
            bf16x8 a0 = *(const bf16x8*)(&Al[pc][(wave * 32 + col_l) * 32 + quad * 8]);
            bf16x8 a1 = *(const bf16x8*)(&Al[pc][(wave * 32 + 16 + col_l) * 32 + quad * 8]);
            bf16x8 b0 = *(const bf16x8*)(&Bl[pc][(col_l) * 32 + quad * 8]);
            bf16x8 b1 = *(const bf16x8*)(&Bl[pc][(16 + col_l) * 32 + quad * 8]);
            acc[0][0] = MFMA16(a0, b0, acc[0][0], 0, 0, 0);
            acc[0][1] = MFMA16(a0, b1, acc[0][1], 0, 0, 0);
            acc[1][0] = MFMA16(a1, b0, acc[1][0], 0, 0, 0);
            acc[1][1] = MFMA16(a1, b1, acc[1][1], 0, 0, 0);
        }
        __syncthreads();
    }
#pragma unroll
    for (int i2 = 0; i2 < 2; i2++)
#pragma unroll
        for (int ck = 0; ck < 2; ck++)
#pragma unroll
            for (int r = 0; r < 4; r++) {
                int c = c0 + wave * 32 + i2 * 16 + quad * 4 + r;
                int k = ck * 16 + col_l;
                atomicAdd(&enc[(size_t)(b * CC + c) * KK + k], acc[i2][ck][r]);
            }
}

// ---------------- K3b: BN1 + ReLU + mean over k -> efeat --------------------
__global__ __launch_bounds__(256) void k_efeat(const float* __restrict__ enc,
                                               const float* __restrict__ asum,
                                               const float* __restrict__ cwf,
                                               const float* __restrict__ s1,
                                               const float* __restrict__ t1,
                                               float* __restrict__ efeat) {
    __shared__ float asl[KK], s1l[KK], t1l[KK];
    int b = blockIdx.x, t = threadIdx.x;
    if (t < KK) { asl[t] = asum[b * KK + t]; s1l[t] = s1[t]; t1l[t] = t1[t]; }
    __syncthreads();
#pragma unroll
    for (int cc = 0; cc < 2; cc++) {
        int c = cc * 256 + t;
        const float* er = enc + (size_t)(b * CC + c) * KK;
        float s = 0.f;
#pragma unroll
        for (int k = 0; k < KK; k++) {
            float v = (er[k] - asl[k] * cwf[k * CC + c]) * s1l[k] + t1l[k];
            s += fmaxf(v, 0.f);
        }
        efeat[b * CC + c] = s * (1.f / 32.f);
    }
}

// ---------------- K4: gamma = sigmoid(efeat @ fc_w^T + fc_b) ----------------
__global__ __launch_bounds__(256) void k_fc(const float* __restrict__ efeat,
                                            const float* __restrict__ fcw,
                                            const float* __restrict__ fcb,
                                            float* __restrict__ gamma) {
    __shared__ float ef[CC];
    int bid = blockIdx.x;
    int b  = bid >> 1;
    int o0 = (bid & 1) * 256;
    int t = threadIdx.x;
    if (t < 128) *(float4*)(&ef[t * 4]) = *(const float4*)(efeat + b * CC + t * 4);
    __syncthreads();
    int o = o0 + t;
    float a = fcb[o];
    const float* wrow = fcw + (size_t)o * CC;
#pragma unroll 4
    for (int c4 = 0; c4 < 128; c4++) {
        float4 w = *(const float4*)(wrow + c4 * 4);
        float4 e = *(const float4*)(&ef[c4 * 4]);
        a += w.x * e.x + w.y * e.y + w.z * e.z + w.w * e.w;
    }
    gamma[b * CC + o] = 1.f / (1.f + __expf(-a));
}

// ---------------- K5: out = relu(x * (1 + gamma[b,c])) ----------------------
// one block per (b,c) row of 4096 floats
__global__ __launch_bounds__(256) void k_gate(const float* __restrict__ x,
                                              const float* __restrict__ gamma,
                                              float* __restrict__ out) {
    int bid = blockIdx.x;                // bid = b*512 + c
    float g = 1.f + gamma[bid];
    const float* xr = x + ((size_t)bid << 12);
    float* orow = out + ((size_t)bid << 12);
    int t4 = threadIdx.x * 4;
#pragma unroll
    for (int u = 0; u < 4; u++) {
        float4 v = *(const float4*)(xr + u * 1024 + t4);
        v.x = fmaxf(v.x * g, 0.f);
        v.y = fmaxf(v.y * g, 0.f);
        v.z = fmaxf(v.z * g, 0.f);
        v.w = fmaxf(v.w * g, 0.f);
        *(float4*)(orow + u * 1024 + t4) = v;
    }
}

extern "C" void kernel_launch(void* const* d_in, const int* in_sizes, int n_in,
                              void* d_out, int out_size, void* d_ws, size_t ws_size,
                              hipStream_t stream) {
    const float* x      = (const float*)d_in[0];
    const float* conv_w = (const float*)d_in[1];
    const float* bn2_g  = (const float*)d_in[2];
    const float* bn2_b  = (const float*)d_in[3];
    const float* bn2_m  = (const float*)d_in[4];
    const float* bn2_v  = (const float*)d_in[5];
    const float* cw     = (const float*)d_in[6];
    const float* scale  = (const float*)d_in[7];
    const float* bn1_g  = (const float*)d_in[8];
    const float* bn1_b  = (const float*)d_in[9];
    const float* bn1_m  = (const float*)d_in[10];
    const float* bn1_v  = (const float*)d_in[11];
    const float* fc_w   = (const float*)d_in[12];
    const float* fc_b   = (const float*)d_in[13];

    float* outf = (float*)d_out;               // [0,8192) efeat, [8192,...) gated output
    char* ws = (char*)d_ws;

    // workspace layout (x2/asum/enc contiguous -> one memset)
    unsigned short* feats   = (unsigned short*)(ws);                    // 67,108,864
    unsigned short* assignT = (unsigned short*)(ws + 67108864);         //  4,194,304
    unsigned short* Wb      = (unsigned short*)(ws + 71303168);         //    524,288
    unsigned short* cwb     = (unsigned short*)(ws + 71827456);         //     32,768
    float*          x2      = (float*)(ws + 71860224);                  //    262,144
    float*          asum    = (float*)(ws + 72122368);                  //      2,048
    float*          enc     = (float*)(ws + 72124416);                  //  1,048,576
    float*          sc2     = (float*)(ws + 73172992);
    float*          s1      = (float*)(ws + 73173248);
    float*          t1      = (float*)(ws + 73173504);
    float*          gamma   = (float*)(ws + 73173760);                  //     32,768

    // xT and featsT live in d_out's output region, overwritten later by k_gate
    unsigned short* xT     = (unsigned short*)((char*)d_out + 32768);     // 67,108,864
    unsigned short* featsT = (unsigned short*)((char*)d_out + 67141632);  // 67,108,864

    hipMemsetAsync(x2, 0, 262144 + 2048 + 1048576, stream);   // x2 + asum + enc

    k_prep<<<273, 256, 0, stream>>>(conv_w, cw, scale, bn1_g, bn1_b, bn1_m, bn1_v,
                                    Wb, cwb, sc2, s1, t1);
    k_transpose<<<8192, 256, 0, stream>>>(x, xT);
    k_conv_gemm<<<2048, 256, 0, stream>>>(xT, Wb, bn2_g, bn2_b, bn2_m, bn2_v,
                                          feats, featsT, x2);
    k_assign<<<512, 256, 0, stream>>>(feats, cwb, x2, scale, sc2, assignT, asum);
    k_encode<<<512, 256, 0, stream>>>(featsT, assignT, enc);
    k_efeat<<<16, 256, 0, stream>>>(enc, asum, cw, s1, t1, outf);
    k_fc<<<32, 256, 0, stream>>>(outf, fc_w, fc_b, gamma);
    k_gate<<<8192, 256, 0, stream>>>(x, gamma, outf + 8192);
}